// Round 9
// baseline (378.850 us; speedup 1.0000x reference)
//
#include <hip/hip_runtime.h>
#include <hip/hip_bf16.h>
#include <math.h>

#define N_NODES 100000
#define N_EDGES 1600000
#define N_POSTS 10000
#define ND 128
#define H 64
#define SCAN_B 1024
#define SCAN_NB ((N_NODES + SCAN_B - 1) / SCAN_B)

typedef __attribute__((ext_vector_type(8))) short bf16x8;
typedef __attribute__((ext_vector_type(4))) float f32x4;

static __device__ __forceinline__ unsigned short f2bf(float f) {
  return __builtin_bit_cast(unsigned short, __float2bfloat16(f));
}

static __device__ __forceinline__ bf16x8 pack8(const float* v) {
  bf16x8 r;
#pragma unroll
  for (int i = 0; i < 8; ++i) r[i] = (short)f2bf(v[i]);
  return r;
}

__device__ __forceinline__ float bcastf(float v, int lane) {
  return __builtin_bit_cast(float, __builtin_amdgcn_readlane(__builtin_bit_cast(int, v), lane));
}

__device__ __forceinline__ int load_idx(const void* p, long long i, int is64) {
  if (is64) return (int)((const long long*)p)[i];
  return ((const int*)p)[i];
}

static __device__ __forceinline__ int imin(int a, int b) { return a < b ? a : b; }

// Fused: zero cnt+pf+Mc (contiguous 2N+1 ints) + int-width detect (block 0).
__global__ void init_kernel(const void* __restrict__ eidx, int* __restrict__ cnt2,
                            int* __restrict__ flag) {
  int i = blockIdx.x * blockDim.x + threadIdx.x;
  if (i < 2 * N_NODES + 1) cnt2[i] = 0;
  if (blockIdx.x == 0 && threadIdx.x < 64) {
    int v = ((const int*)eidx)[2 * threadIdx.x + 1];
    unsigned long long b = __ballot(v != 0);
    if (threadIdx.x == 0) flag[0] = (b == 0ULL) ? 1 : 0; // 1 => int64 layout
  }
}

// Mark posted nodes
__global__ void mark_kernel(const void* __restrict__ pidx, int* __restrict__ pf,
                            const int* __restrict__ flag) {
  const int is64 = flag[0];
  int i = blockIdx.x * blockDim.x + threadIdx.x;
  if (i < N_POSTS) pf[load_idx(pidx, i, is64)] = 1;
}

// Single pass over eidx: compact passing (posted-dst) edges into cT (unordered,
// atomic cursor Mc) AND build the dst histogram.
__global__ void compact_hist_kernel(const void* __restrict__ eidx,
                                    const int* __restrict__ pf, int* __restrict__ cnt,
                                    int4* __restrict__ cT, int* __restrict__ Mc,
                                    const int* __restrict__ flag) {
  const int is64 = flag[0];
  int i = blockIdx.x * blockDim.x + threadIdx.x;
  const int stride = gridDim.x * blockDim.x;
  for (; i < N_EDGES; i += stride) {
    int d = load_idx(eidx, (long long)N_EDGES + i, is64);
    if (pf[d]) {
      int s = load_idx(eidx, i, is64);
      atomicAdd(&cnt[d], 1);
      int pos = atomicAdd(Mc, 1);
      cT[pos] = make_int4(i, s, d, 0);
    }
  }
}

// Two-level scan, pass 1: per-block coalesced exclusive scan + RAW block totals.
__global__ void __launch_bounds__(SCAN_B) scan_block_kernel(int* __restrict__ cnt,
                                                            int* __restrict__ btot) {
  __shared__ int wsum[16];
  const int i = blockIdx.x * SCAN_B + threadIdx.x;
  const int lane = threadIdx.x & 63;
  const int wv = threadIdx.x >> 6;
  const int x = (i < N_NODES) ? cnt[i] : 0;
  int s = x;
#pragma unroll
  for (int off = 1; off < 64; off <<= 1) {
    int y = __shfl_up(s, off, 64);
    if (lane >= off) s += y;
  }
  if (lane == 63) wsum[wv] = s;
  __syncthreads();
  if (wv == 0) {
    int t = (lane < 16) ? wsum[lane] : 0;
#pragma unroll
    for (int off = 1; off < 16; off <<= 1) {
      int y = __shfl_up(t, off, 64);
      if (lane >= off) t += y;
    }
    if (lane < 16) wsum[lane] = t;
  }
  __syncthreads();
  const int woff = (wv == 0) ? 0 : wsum[wv - 1];
  if (i < N_NODES) cnt[i] = woff + s - x; // exclusive within block
  if (threadIdx.x == 0) btot[blockIdx.x] = wsum[15]; // raw total
}

// Pass 2 (merged): each block locally scans the raw block totals, adds its
// exclusive offset to cnt.
__global__ void __launch_bounds__(SCAN_B) scan_add_kernel(int* __restrict__ cnt,
                                                          const int* __restrict__ btot) {
  __shared__ int buf[128];
  if (threadIdx.x < 128) buf[threadIdx.x] = (threadIdx.x < SCAN_NB) ? btot[threadIdx.x] : 0;
  __syncthreads();
#pragma unroll
  for (int off = 1; off < 128; off <<= 1) {
    int y = 0;
    if (threadIdx.x < 128 && threadIdx.x >= off) y = buf[threadIdx.x - off];
    __syncthreads();
    if (threadIdx.x < 128) buf[threadIdx.x] += y;
    __syncthreads();
  }
  const int i = blockIdx.x * SCAN_B + threadIdx.x;
  const int excl = (blockIdx.x == 0) ? 0 : buf[blockIdx.x - 1];
  if (i < N_NODES) cnt[i] += excl;
}

// Scatter compacted tuples into dst-sorted order (reads 2.4MB, not 25.6MB).
__global__ void scatter_kernel(const int4* __restrict__ cT, int* __restrict__ ofs,
                               int4* __restrict__ eS, const int* __restrict__ Mc) {
  const int M = Mc[0];
  int i = blockIdx.x * blockDim.x + threadIdx.x;
  const int stride = gridDim.x * blockDim.x;
  for (; i < M; i += stride) {
    int4 t = cT[i];
    int pos = atomicAdd(&ofs[t.z], 1);
    eS[pos] = t;
  }
}

// MFMA node pipeline: 16 nodes/wave-tile.
// GEMM1: emb^T = relu(Wn @ nf^T + bn)  (K=128, 4 k-steps)
// GEMM2: T2^T  = Wc[:, :H] @ emb + bc  (lane-local chaining, K=64)
// acc rows stored only for posted nodes (pf ballot mask); T2 for all.
__global__ void __launch_bounds__(256, 2) node_kernel_mfma(
    const float* __restrict__ nf, const float* __restrict__ Wn,
    const float* __restrict__ bn, const float* __restrict__ Wc,
    const float* __restrict__ bc, const int* __restrict__ pf,
    float* __restrict__ acc, float* __restrict__ T2) {
  __shared__ float lds[4][64 * 17];
  __shared__ __attribute__((aligned(16))) float bshn[64];
  __shared__ __attribute__((aligned(16))) float bshc[64];
  const int lane = threadIdx.x & 63;
  const int wslot = threadIdx.x >> 6;
  float* myl = lds[wslot];
  const int wid = blockIdx.x * 4 + wslot;
  const int nw = gridDim.x * 4;
  const int e16 = lane & 15; // node-in-tile
  const int g = lane >> 4;   // k-group / row-group

  if (threadIdx.x < 64) {
    bshn[threadIdx.x] = bn[threadIdx.x];
    bshc[threadIdx.x] = bc[threadIdx.x];
  }

  // Weight fragments (k-map per 32-k step t: elem i -> k = t*32 + (i>>2)*16 + g*4 + (i&3))
  bf16x8 wN[4][4], wC1[4][2];
#pragma unroll
  for (int mt = 0; mt < 4; ++mt) {
#pragma unroll
    for (int t = 0; t < 4; ++t) {
      float tmp[8];
      const float* rowA = Wn + (mt * 16 + e16) * ND + t * 32 + g * 4;
      *(f32x4*)(tmp) = *(const f32x4*)(rowA);
      *(f32x4*)(tmp + 4) = *(const f32x4*)(rowA + 16);
      wN[mt][t] = pack8(tmp);
    }
#pragma unroll
    for (int t = 0; t < 2; ++t) {
      float tmp[8];
      const float* rowC = Wc + (mt * 16 + e16) * (2 * H) + t * 32 + g * 4;
      *(f32x4*)(tmp) = *(const f32x4*)(rowC);
      *(f32x4*)(tmp + 4) = *(const f32x4*)(rowC + 16);
      wC1[mt][t] = pack8(tmp);
    }
  }
  __syncthreads();

  const int NTN = N_NODES / 16; // 6250
  for (int tile = wid; tile < NTN; tile += nw) {
    const int n0 = tile * 16;
    const float* base = nf + (long long)(n0 + e16) * ND;

    // B1 fragments from node_features (fp32 -> bf16), 4 k-steps
    bf16x8 b1[4];
#pragma unroll
    for (int t = 0; t < 4; ++t) {
      float tmp[8];
      *(f32x4*)(tmp) = *(const f32x4*)(base + t * 32 + g * 4);
      *(f32x4*)(tmp + 4) = *(const f32x4*)(base + t * 32 + 16 + g * 4);
      b1[t] = pack8(tmp);
    }

    // GEMM1: emb = relu(Wn @ nf^T + bn)
    f32x4 d1[4];
#pragma unroll
    for (int mt = 0; mt < 4; ++mt) d1[mt] = *(const f32x4*)(bshn + mt * 16 + g * 4);
#pragma unroll
    for (int t = 0; t < 4; ++t)
#pragma unroll
      for (int mt = 0; mt < 4; ++mt)
        d1[mt] = __builtin_amdgcn_mfma_f32_16x16x32_bf16(wN[mt][t], b1[t], d1[mt], 0, 0, 0);

    // relu in-place; lane-local chain into GEMM2 B operand
#pragma unroll
    for (int mt = 0; mt < 4; ++mt)
#pragma unroll
      for (int r = 0; r < 4; ++r) d1[mt][r] = fmaxf(d1[mt][r], 0.f);

    bf16x8 b2[2];
#pragma unroll
    for (int t = 0; t < 2; ++t) {
      float tmp[8];
#pragma unroll
      for (int i = 0; i < 4; ++i) {
        tmp[i] = d1[2 * t][i];
        tmp[4 + i] = d1[2 * t + 1][i];
      }
      b2[t] = pack8(tmp);
    }

    // GEMM2: T2 = Wc[:, :H] @ emb + bc
    f32x4 d2[4];
#pragma unroll
    for (int mt = 0; mt < 4; ++mt) d2[mt] = *(const f32x4*)(bshc + mt * 16 + g * 4);
#pragma unroll
    for (int t = 0; t < 2; ++t)
#pragma unroll
      for (int mt = 0; mt < 4; ++mt)
        d2[mt] = __builtin_amdgcn_mfma_f32_16x16x32_bf16(wC1[mt][t], b2[t], d2[mt], 0, 0, 0);

    // Posted-node mask for gated acc stores (bits 0..15)
    const unsigned long long pmask = __ballot(lane < 16 && pf[n0 + lane] != 0);

    // Pass 1: emb -> LDS transpose -> gated acc rows
#pragma unroll
    for (int mt = 0; mt < 4; ++mt)
#pragma unroll
      for (int r = 0; r < 4; ++r)
        myl[(mt * 16 + g * 4 + r) * 17 + e16] = d1[mt][r];
#pragma unroll
    for (int e = 0; e < 16; ++e)
      if ((pmask >> e) & 1)
        acc[(long long)(n0 + e) * H + lane] = myl[lane * 17 + e];

    // Pass 2: T2 -> LDS transpose -> all rows
#pragma unroll
    for (int mt = 0; mt < 4; ++mt)
#pragma unroll
      for (int r = 0; r < 4; ++r)
        myl[(mt * 16 + g * 4 + r) * 17 + e16] = d2[mt][r];
#pragma unroll
    for (int e = 0; e < 16; ++e)
      T2[(long long)(n0 + e) * H + lane] = myl[lane * 17 + e];
  }
}

// Sorted-order MFMA edge pipeline over the M filtered (posted-dst) edges.
__global__ void __launch_bounds__(256, 2) edge_kernel_sorted(
    const float* __restrict__ ea, const float* __restrict__ We,
    const float* __restrict__ be, const float* __restrict__ Wc,
    const float* __restrict__ T2, float* __restrict__ acc,
    const int4* __restrict__ eS, const int* __restrict__ Mp) {
  __shared__ float lds[4][64 * 17];
  __shared__ __attribute__((aligned(16))) float bsh[64];
  const int lane = threadIdx.x & 63;
  const int wslot = threadIdx.x >> 6;
  float* myl = lds[wslot];
  const int wid = blockIdx.x * 4 + wslot;
  const int nw = gridDim.x * 4;
  const int e16 = lane & 15;
  const int g = lane >> 4;

  if (threadIdx.x < 64) bsh[threadIdx.x] = be[threadIdx.x];

  bf16x8 wA[4][2], wC[4][2];
#pragma unroll
  for (int mt = 0; mt < 4; ++mt) {
#pragma unroll
    for (int t = 0; t < 2; ++t) {
      float tmp[8];
      const float* rowA = We + (mt * 16 + e16) * H + t * 32 + g * 4;
      *(f32x4*)(tmp) = *(const f32x4*)(rowA);
      *(f32x4*)(tmp + 4) = *(const f32x4*)(rowA + 16);
      wA[mt][t] = pack8(tmp);
      const float* rowC = Wc + (mt * 16 + e16) * (2 * H) + H + t * 32 + g * 4;
      *(f32x4*)(tmp) = *(const f32x4*)(rowC);
      *(f32x4*)(tmp + 4) = *(const f32x4*)(rowC + 16);
      wC[mt][t] = pack8(tmp);
    }
  }
  __syncthreads();

  const int M = Mp[0];
  const int ntiles = (M + 15) >> 4;
  const int chunk = (ntiles + nw - 1) / nw;
  const int t0 = wid * chunk;
  const int t1 = imin(t0 + chunk, ntiles);
  if (t0 >= t1) return;

  // Prologue: current tuple + ea data; next tuple. Clamp tail lanes.
  int4 eC = make_int4(0, 0, 0, 0);
  {
    const int i0 = t0 * 16 + e16;
    if (i0 < M) eC = eS[i0];
  }
  f32x4 eaC[4];
  {
    const float* base = ea + (long long)eC.x * H;
    eaC[0] = *(const f32x4*)(base + g * 4);
    eaC[1] = *(const f32x4*)(base + 16 + g * 4);
    eaC[2] = *(const f32x4*)(base + 32 + g * 4);
    eaC[3] = *(const f32x4*)(base + 48 + g * 4);
  }
  int4 eN = eC;
  if (t0 + 1 < t1) {
    const int i1 = (t0 + 1) * 16 + e16;
    eN = (i1 < M) ? eS[i1] : make_int4(0, 0, 0, 0);
  }

  int run_d = -1;
  float run_v = 0.f;

  for (int tile = t0; tile < t1; ++tile) {
    bf16x8 b1[2];
#pragma unroll
    for (int t = 0; t < 2; ++t) {
      float tmp[8];
#pragma unroll
      for (int i = 0; i < 4; ++i) {
        tmp[i] = eaC[t * 2][i];
        tmp[4 + i] = eaC[t * 2 + 1][i];
      }
      b1[t] = pack8(tmp);
    }
    const int srcc = eC.y;
    const int dstc = eC.z;

    if (tile + 1 < t1) {
      const float* base = ea + (long long)eN.x * H;
      eaC[0] = *(const f32x4*)(base + g * 4);
      eaC[1] = *(const f32x4*)(base + 16 + g * 4);
      eaC[2] = *(const f32x4*)(base + 32 + g * 4);
      eaC[3] = *(const f32x4*)(base + 48 + g * 4);
    }
    eC = eN;
    if (tile + 2 < t1) {
      const int i2 = (tile + 2) * 16 + e16;
      eN = (i2 < M) ? eS[i2] : make_int4(0, 0, 0, 0);
    }

    // GEMM1: he = relu(We @ ea^T + be)
    f32x4 d1[4];
#pragma unroll
    for (int mt = 0; mt < 4; ++mt) d1[mt] = *(const f32x4*)(bsh + mt * 16 + g * 4);
#pragma unroll
    for (int t = 0; t < 2; ++t)
#pragma unroll
      for (int mt = 0; mt < 4; ++mt)
        d1[mt] = __builtin_amdgcn_mfma_f32_16x16x32_bf16(wA[mt][t], b1[t], d1[mt], 0, 0, 0);

    bf16x8 b2[2];
#pragma unroll
    for (int t = 0; t < 2; ++t) {
      float tmp[8];
#pragma unroll
      for (int i = 0; i < 4; ++i) {
        tmp[i] = fmaxf(d1[2 * t][i], 0.f);
        tmp[4 + i] = fmaxf(d1[2 * t + 1][i], 0.f);
      }
      b2[t] = pack8(tmp);
    }

    // GEMM2 streamed per-mt into LDS transpose (stride 17)
#pragma unroll
    for (int mt = 0; mt < 4; ++mt) {
      f32x4 d2 = (f32x4){0.f, 0.f, 0.f, 0.f};
      d2 = __builtin_amdgcn_mfma_f32_16x16x32_bf16(wC[mt][0], b2[0], d2, 0, 0, 0);
      d2 = __builtin_amdgcn_mfma_f32_16x16x32_bf16(wC[mt][1], b2[1], d2, 0, 0, 0);
#pragma unroll
      for (int r = 0; r < 4; ++r)
        myl[(mt * 16 + g * 4 + r) * 17 + e16] = d2[r];
    }

    // Scatter: 8 independent T2 gathers in flight, then register run-accumulate.
    const int nval = imin(16, M - tile * 16);
#pragma unroll
    for (int half = 0; half < 2; ++half) {
      float mv[8];
#pragma unroll
      for (int e = 0; e < 8; ++e) {
        const int s = __builtin_amdgcn_readlane(srcc, half * 8 + e);
        mv[e] = myl[lane * 17 + half * 8 + e] + T2[(long long)s * H + lane];
      }
      const int hi = imin(8, nval - half * 8);
      for (int e = 0; e < hi; ++e) {
        const int d = __builtin_amdgcn_readlane(dstc, half * 8 + e);
        if (d != run_d) {
          if (run_d >= 0) atomicAdd(&acc[(long long)run_d * H + lane], run_v);
          run_d = d;
          run_v = mv[e];
        } else {
          run_v += mv[e];
        }
      }
    }
  }
  if (run_d >= 0) atomicAdd(&acc[(long long)run_d * H + lane], run_v);
}

// ---- Fallback path (unfiltered, fp32 node) — only if ws can't fit buffers ----
__global__ void __launch_bounds__(256, 2) node_kernel(
    const float* __restrict__ nf, const float* __restrict__ Wn,
    const float* __restrict__ bn, const float* __restrict__ Wc,
    const float* __restrict__ bc, float* __restrict__ acc,
    float* __restrict__ T2) {
  const int lane = threadIdx.x & 63;
  const int wid = blockIdx.x * (blockDim.x >> 6) + (threadIdx.x >> 6);
  const int nw = gridDim.x * (blockDim.x >> 6);

  float wn[ND];
#pragma unroll
  for (int i = 0; i < ND / 4; ++i) {
    float4 v = ((const float4*)(Wn + lane * ND))[i];
    wn[4 * i] = v.x; wn[4 * i + 1] = v.y; wn[4 * i + 2] = v.z; wn[4 * i + 3] = v.w;
  }
  float wc[H];
#pragma unroll
  for (int i = 0; i < H / 4; ++i) {
    float4 v = ((const float4*)(Wc + lane * 2 * H))[i];
    wc[4 * i] = v.x; wc[4 * i + 1] = v.y; wc[4 * i + 2] = v.z; wc[4 * i + 3] = v.w;
  }
  const float bnl = bn[lane];
  const float bcl = bc[lane];

  for (int n = wid; n < N_NODES; n += nw) {
    const float xa = nf[(long long)n * ND + lane];
    const float xb = nf[(long long)n * ND + 64 + lane];
    float a0 = 0.f, a1 = 0.f, a2 = 0.f, a3 = 0.f;
#pragma unroll
    for (int k = 0; k < 64; k += 4) {
      a0 = fmaf(bcastf(xa, k + 0), wn[k + 0], a0);
      a1 = fmaf(bcastf(xa, k + 1), wn[k + 1], a1);
      a2 = fmaf(bcastf(xa, k + 2), wn[k + 2], a2);
      a3 = fmaf(bcastf(xa, k + 3), wn[k + 3], a3);
    }
#pragma unroll
    for (int k = 0; k < 64; k += 4) {
      a0 = fmaf(bcastf(xb, k + 0), wn[64 + k + 0], a0);
      a1 = fmaf(bcastf(xb, k + 1), wn[64 + k + 1], a1);
      a2 = fmaf(bcastf(xb, k + 2), wn[64 + k + 2], a2);
      a3 = fmaf(bcastf(xb, k + 3), wn[64 + k + 3], a3);
    }
    float e = fmaxf(a0 + a1 + a2 + a3 + bnl, 0.f);

    float t0 = 0.f, t1 = 0.f, t2 = 0.f, t3 = 0.f;
#pragma unroll
    for (int j = 0; j < 64; j += 4) {
      t0 = fmaf(bcastf(e, j + 0), wc[j + 0], t0);
      t1 = fmaf(bcastf(e, j + 1), wc[j + 1], t1);
      t2 = fmaf(bcastf(e, j + 2), wc[j + 2], t2);
      t3 = fmaf(bcastf(e, j + 3), wc[j + 3], t3);
    }
    float t = t0 + t1 + t2 + t3 + bcl;

    acc[(long long)n * H + lane] = e;
    T2[(long long)n * H + lane] = t;
  }
}

__global__ void __launch_bounds__(256, 2) edge_kernel(
    const void* __restrict__ eidx, const float* __restrict__ ea,
    const float* __restrict__ We, const float* __restrict__ be,
    const float* __restrict__ Wc, const float* __restrict__ T2,
    float* __restrict__ acc, const int* __restrict__ flag) {
  __shared__ float lds[4][64 * 17];
  const int lane = threadIdx.x & 63;
  const int wslot = threadIdx.x >> 6;
  float* myl = lds[wslot];
  const int wid = blockIdx.x * 4 + wslot;
  const int nw = gridDim.x * 4;
  const int is64 = flag[0];
  const int e16 = lane & 15;
  const int g = lane >> 4;
  const int NT = N_EDGES / 16;

  bf16x8 wA[4][2], wC[4][2];
#pragma unroll
  for (int mt = 0; mt < 4; ++mt) {
#pragma unroll
    for (int t = 0; t < 2; ++t) {
      float tmp[8];
      const float* rowA = We + (mt * 16 + e16) * H + t * 32 + g * 4;
      *(f32x4*)(tmp) = *(const f32x4*)(rowA);
      *(f32x4*)(tmp + 4) = *(const f32x4*)(rowA + 16);
      wA[mt][t] = pack8(tmp);
      const float* rowC = Wc + (mt * 16 + e16) * (2 * H) + H + t * 32 + g * 4;
      *(f32x4*)(tmp) = *(const f32x4*)(rowC);
      *(f32x4*)(tmp + 4) = *(const f32x4*)(rowC + 16);
      wC[mt][t] = pack8(tmp);
    }
  }
  f32x4 bias[4];
#pragma unroll
  for (int mt = 0; mt < 4; ++mt)
#pragma unroll
    for (int r = 0; r < 4; ++r) bias[mt][r] = be[mt * 16 + g * 4 + r];

  f32x4 ean[4];
  int srcn = 0, dstn = 0;
  int tile = wid;
  if (tile < NT) {
    const float* base = ea + (long long)(tile * 16 + e16) * H;
#pragma unroll
    for (int t = 0; t < 2; ++t) {
      ean[t * 2] = *(const f32x4*)(base + t * 32 + g * 4);
      ean[t * 2 + 1] = *(const f32x4*)(base + t * 32 + 16 + g * 4);
    }
    srcn = load_idx(eidx, (long long)tile * 16 + e16, is64);
    dstn = load_idx(eidx, (long long)N_EDGES + (long long)tile * 16 + e16, is64);
  }

  for (; tile < NT; tile += nw) {
    f32x4 eac[4];
#pragma unroll
    for (int i = 0; i < 4; ++i) eac[i] = ean[i];
    const int srcc = srcn, dstc = dstn;

    const int tn = tile + nw;
    if (tn < NT) {
      const float* base = ea + (long long)(tn * 16 + e16) * H;
#pragma unroll
      for (int t = 0; t < 2; ++t) {
        ean[t * 2] = *(const f32x4*)(base + t * 32 + g * 4);
        ean[t * 2 + 1] = *(const f32x4*)(base + t * 32 + 16 + g * 4);
      }
      srcn = load_idx(eidx, (long long)tn * 16 + e16, is64);
      dstn = load_idx(eidx, (long long)N_EDGES + (long long)tn * 16 + e16, is64);
    }

    bf16x8 b1[2];
#pragma unroll
    for (int t = 0; t < 2; ++t) {
      float tmp[8];
#pragma unroll
      for (int i = 0; i < 4; ++i) {
        tmp[i] = eac[t * 2][i];
        tmp[4 + i] = eac[t * 2 + 1][i];
      }
      b1[t] = pack8(tmp);
    }

    f32x4 d1[4];
#pragma unroll
    for (int mt = 0; mt < 4; ++mt) d1[mt] = bias[mt];
#pragma unroll
    for (int t = 0; t < 2; ++t)
#pragma unroll
      for (int mt = 0; mt < 4; ++mt)
        d1[mt] = __builtin_amdgcn_mfma_f32_16x16x32_bf16(wA[mt][t], b1[t], d1[mt], 0, 0, 0);

    bf16x8 b2[2];
#pragma unroll
    for (int t = 0; t < 2; ++t) {
      float tmp[8];
#pragma unroll
      for (int i = 0; i < 4; ++i) {
        tmp[i] = fmaxf(d1[2 * t][i], 0.f);
        tmp[4 + i] = fmaxf(d1[2 * t + 1][i], 0.f);
      }
      b2[t] = pack8(tmp);
    }

    f32x4 d2[4];
#pragma unroll
    for (int mt = 0; mt < 4; ++mt) d2[mt] = (f32x4){0.f, 0.f, 0.f, 0.f};
#pragma unroll
    for (int t = 0; t < 2; ++t)
#pragma unroll
      for (int mt = 0; mt < 4; ++mt)
        d2[mt] = __builtin_amdgcn_mfma_f32_16x16x32_bf16(wC[mt][t], b2[t], d2[mt], 0, 0, 0);

#pragma unroll
    for (int mt = 0; mt < 4; ++mt)
#pragma unroll
      for (int r = 0; r < 4; ++r)
        myl[(mt * 16 + g * 4 + r) * 17 + e16] = d2[mt][r];

#pragma unroll
    for (int e = 0; e < 16; ++e) {
      const int s = __builtin_amdgcn_readlane(srcc, e);
      const int d = __builtin_amdgcn_readlane(dstc, e);
      const float m = myl[lane * 17 + e] + T2[(long long)s * H + lane];
      atomicAdd(&acc[(long long)d * H + lane], m);
    }
  }
}

// Per-post: logit = dot(acc[idx], W_out) + b_out; out = sigmoid(logit)
__global__ void __launch_bounds__(256) out_kernel(
    const void* __restrict__ pidx, const float* __restrict__ acc,
    const float* __restrict__ Wo, const float* __restrict__ bo,
    float* __restrict__ out, const int* __restrict__ flag) {
  const int lane = threadIdx.x & 63;
  const int w = blockIdx.x * (blockDim.x >> 6) + (threadIdx.x >> 6);
  if (w >= N_POSTS) return;
  const int is64 = flag[0];
  const int idx = load_idx(pidx, w, is64);
  float v = acc[(long long)idx * H + lane] * Wo[lane];
#pragma unroll
  for (int s = 32; s > 0; s >>= 1) v += __shfl_xor(v, s, 64);
  if (lane == 0) {
    float logit = v + bo[0];
    out[w] = 1.f / (1.f + expf(-logit));
  }
}

extern "C" void kernel_launch(void* const* d_in, const int* in_sizes, int n_in,
                              void* d_out, int out_size, void* d_ws, size_t ws_size,
                              hipStream_t stream) {
  const float* nf = (const float*)d_in[0];
  const void* eidx = d_in[1];
  const float* ea = (const float*)d_in[2];
  const void* pidx = d_in[3];
  const float* Wn = (const float*)d_in[4];
  const float* bn = (const float*)d_in[5];
  const float* We = (const float*)d_in[6];
  const float* be = (const float*)d_in[7];
  const float* Wc = (const float*)d_in[8];
  const float* bc = (const float*)d_in[9];
  const float* Wo = (const float*)d_in[10];
  const float* bo = (const float*)d_in[11];
  float* out = (float*)d_out;

  float* acc = (float*)d_ws;                     // [N,H]
  float* T2 = acc + (size_t)N_NODES * H;         // [N,H]
  int4* eS = (int4*)(T2 + (size_t)N_NODES * H);  // [E] sorted tuples, 16B-aligned
  int4* cT = eS + N_EDGES;                       // [E] compacted (unordered) tuples
  int* cnt = (int*)(cT + N_EDGES);               // [N]
  int* pf = cnt + N_NODES;                       // [N] posted-node flags
  int* Mc = pf + N_NODES;                        // [1] compacted count (zeroed w/ cnt+pf)
  int* btot = Mc + 1;                            // [128]
  int* flag = btot + 128;                        // [1]

  const size_t need_sorted = (size_t)2 * N_NODES * H * 4 + (size_t)2 * N_EDGES * 16 +
                             (size_t)2 * N_NODES * 4 + 4 + 128 * 4 + 4;

  if (ws_size >= need_sorted) {
    init_kernel<<<(2 * N_NODES + 256) / 256, 256, 0, stream>>>(eidx, cnt, flag);
    mark_kernel<<<(N_POSTS + 255) / 256, 256, 0, stream>>>(pidx, pf, flag);
    compact_hist_kernel<<<2048, 256, 0, stream>>>(eidx, pf, cnt, cT, Mc, flag);
    scan_block_kernel<<<SCAN_NB, SCAN_B, 0, stream>>>(cnt, btot);
    scan_add_kernel<<<SCAN_NB, SCAN_B, 0, stream>>>(cnt, btot);
    scatter_kernel<<<512, 256, 0, stream>>>(cT, cnt, eS, Mc);
    node_kernel_mfma<<<512, 256, 0, stream>>>(nf, Wn, bn, Wc, bc, pf, acc, T2);
    edge_kernel_sorted<<<512, 256, 0, stream>>>(ea, We, be, Wc, T2, acc, eS, Mc);
    out_kernel<<<(N_POSTS + 3) / 4, 256, 0, stream>>>(pidx, acc, Wo, bo, out, flag);
  } else {
    int* flag2 = (int*)(T2 + (size_t)N_NODES * H);
    init_kernel<<<1, 256, 0, stream>>>(eidx, flag2 - 1, flag2); // detect only
    node_kernel<<<1024, 256, 0, stream>>>(nf, Wn, bn, Wc, bc, acc, T2);
    edge_kernel<<<1024, 256, 0, stream>>>(eidx, ea, We, be, Wc, T2, acc, flag2);
    out_kernel<<<(N_POSTS + 3) / 4, 256, 0, stream>>>(pidx, acc, Wo, bo, out, flag2);
  }
}

// Round 10
// 102.800 us; speedup vs baseline: 3.6853x; 3.6853x over previous
//
#include <hip/hip_runtime.h>
#include <hip/hip_bf16.h>
#include <math.h>

#define N_NODES 100000
#define N_EDGES 1600000
#define N_POSTS 10000
#define ND 128
#define H 64
#define SCAN_B 1024
#define SCAN_NB ((N_NODES + SCAN_B - 1) / SCAN_B)

typedef __attribute__((ext_vector_type(8))) short bf16x8;
typedef __attribute__((ext_vector_type(4))) float f32x4;

static __device__ __forceinline__ unsigned short f2bf(float f) {
  return __builtin_bit_cast(unsigned short, __float2bfloat16(f));
}

static __device__ __forceinline__ bf16x8 pack8(const float* v) {
  bf16x8 r;
#pragma unroll
  for (int i = 0; i < 8; ++i) r[i] = (short)f2bf(v[i]);
  return r;
}

__device__ __forceinline__ float bcastf(float v, int lane) {
  return __builtin_bit_cast(float, __builtin_amdgcn_readlane(__builtin_bit_cast(int, v), lane));
}

__device__ __forceinline__ int load_idx(const void* p, long long i, int is64) {
  if (is64) return (int)((const long long*)p)[i];
  return ((const int*)p)[i];
}

static __device__ __forceinline__ int imin(int a, int b) { return a < b ? a : b; }

// Fused: zero cnt+pf (contiguous 2N ints) + int-width detect (block 0).
__global__ void init_kernel(const void* __restrict__ eidx, int* __restrict__ cnt2,
                            int* __restrict__ flag) {
  int i = blockIdx.x * blockDim.x + threadIdx.x;
  if (i < 2 * N_NODES) cnt2[i] = 0;
  if (blockIdx.x == 0 && threadIdx.x < 64) {
    int v = ((const int*)eidx)[2 * threadIdx.x + 1];
    unsigned long long b = __ballot(v != 0);
    if (threadIdx.x == 0) flag[0] = (b == 0ULL) ? 1 : 0; // 1 => int64 layout
  }
}

// Mark posted nodes
__global__ void mark_kernel(const void* __restrict__ pidx, int* __restrict__ pf,
                            const int* __restrict__ flag) {
  const int is64 = flag[0];
  int i = blockIdx.x * blockDim.x + threadIdx.x;
  if (i < N_POSTS) pf[load_idx(pidx, i, is64)] = 1;
}

// Histogram of dst over posted-dst edges only (distributed-address atomics).
__global__ void hist_kernel(const void* __restrict__ eidx, int* __restrict__ cnt,
                            const int* __restrict__ pf, const int* __restrict__ flag) {
  const int is64 = flag[0];
  int i = blockIdx.x * blockDim.x + threadIdx.x;
  const int stride = gridDim.x * blockDim.x;
  for (; i < N_EDGES; i += stride) {
    int d = load_idx(eidx, (long long)N_EDGES + i, is64);
    if (pf[d]) atomicAdd(&cnt[d], 1);
  }
}

// Two-level scan, pass 1: per-block coalesced exclusive scan + RAW block totals.
__global__ void __launch_bounds__(SCAN_B) scan_block_kernel(int* __restrict__ cnt,
                                                            int* __restrict__ btot) {
  __shared__ int wsum[16];
  const int i = blockIdx.x * SCAN_B + threadIdx.x;
  const int lane = threadIdx.x & 63;
  const int wv = threadIdx.x >> 6;
  const int x = (i < N_NODES) ? cnt[i] : 0;
  int s = x;
#pragma unroll
  for (int off = 1; off < 64; off <<= 1) {
    int y = __shfl_up(s, off, 64);
    if (lane >= off) s += y;
  }
  if (lane == 63) wsum[wv] = s;
  __syncthreads();
  if (wv == 0) {
    int t = (lane < 16) ? wsum[lane] : 0;
#pragma unroll
    for (int off = 1; off < 16; off <<= 1) {
      int y = __shfl_up(t, off, 64);
      if (lane >= off) t += y;
    }
    if (lane < 16) wsum[lane] = t;
  }
  __syncthreads();
  const int woff = (wv == 0) ? 0 : wsum[wv - 1];
  if (i < N_NODES) cnt[i] = woff + s - x; // exclusive within block
  if (threadIdx.x == 0) btot[blockIdx.x] = wsum[15]; // raw total
}

// Pass 2 (merged): each block locally scans the raw block totals, adds its
// exclusive offset to cnt; block 0 also writes total filtered count M.
__global__ void __launch_bounds__(SCAN_B) scan_add_kernel(int* __restrict__ cnt,
                                                          const int* __restrict__ btot,
                                                          int* __restrict__ Mp) {
  __shared__ int buf[128];
  if (threadIdx.x < 128) buf[threadIdx.x] = (threadIdx.x < SCAN_NB) ? btot[threadIdx.x] : 0;
  __syncthreads();
#pragma unroll
  for (int off = 1; off < 128; off <<= 1) {
    int y = 0;
    if (threadIdx.x < 128 && threadIdx.x >= off) y = buf[threadIdx.x - off];
    __syncthreads();
    if (threadIdx.x < 128) buf[threadIdx.x] += y;
    __syncthreads();
  }
  // buf = inclusive scan of raw totals
  const int i = blockIdx.x * SCAN_B + threadIdx.x;
  const int excl = (blockIdx.x == 0) ? 0 : buf[blockIdx.x - 1];
  if (i < N_NODES) cnt[i] += excl;
  if (blockIdx.x == 0 && threadIdx.x == 0) Mp[0] = buf[SCAN_NB - 1];
}

// Scatter (edge_id, src, dst) of posted-dst edges into dst-sorted order.
// Per-dst offset cursors are distributed addresses — no hot-spot.
__global__ void scatter_kernel(const void* __restrict__ eidx, int* __restrict__ ofs,
                               const int* __restrict__ pf, int4* __restrict__ eS,
                               const int* __restrict__ flag) {
  const int is64 = flag[0];
  int i = blockIdx.x * blockDim.x + threadIdx.x;
  const int stride = gridDim.x * blockDim.x;
  for (; i < N_EDGES; i += stride) {
    int d = load_idx(eidx, (long long)N_EDGES + i, is64);
    if (pf[d]) {
      int s = load_idx(eidx, i, is64);
      int pos = atomicAdd(&ofs[d], 1);
      eS[pos] = make_int4(i, s, d, 0);
    }
  }
}

// MFMA node pipeline: 16 nodes/wave-tile.
// GEMM1: emb^T = relu(Wn @ nf^T + bn)  (K=128, 4 k-steps)
// GEMM2: T2^T  = Wc[:, :H] @ emb + bc  (lane-local chaining, K=64)
// acc rows stored only for posted nodes (pf ballot mask); T2 for all.
__global__ void __launch_bounds__(256, 2) node_kernel_mfma(
    const float* __restrict__ nf, const float* __restrict__ Wn,
    const float* __restrict__ bn, const float* __restrict__ Wc,
    const float* __restrict__ bc, const int* __restrict__ pf,
    float* __restrict__ acc, float* __restrict__ T2) {
  __shared__ float lds[4][64 * 17];
  __shared__ __attribute__((aligned(16))) float bshn[64];
  __shared__ __attribute__((aligned(16))) float bshc[64];
  const int lane = threadIdx.x & 63;
  const int wslot = threadIdx.x >> 6;
  float* myl = lds[wslot];
  const int wid = blockIdx.x * 4 + wslot;
  const int nw = gridDim.x * 4;
  const int e16 = lane & 15; // node-in-tile
  const int g = lane >> 4;   // k-group / row-group

  if (threadIdx.x < 64) {
    bshn[threadIdx.x] = bn[threadIdx.x];
    bshc[threadIdx.x] = bc[threadIdx.x];
  }

  // Weight fragments (k-map per 32-k step t: elem i -> k = t*32 + (i>>2)*16 + g*4 + (i&3))
  bf16x8 wN[4][4], wC1[4][2];
#pragma unroll
  for (int mt = 0; mt < 4; ++mt) {
#pragma unroll
    for (int t = 0; t < 4; ++t) {
      float tmp[8];
      const float* rowA = Wn + (mt * 16 + e16) * ND + t * 32 + g * 4;
      *(f32x4*)(tmp) = *(const f32x4*)(rowA);
      *(f32x4*)(tmp + 4) = *(const f32x4*)(rowA + 16);
      wN[mt][t] = pack8(tmp);
    }
#pragma unroll
    for (int t = 0; t < 2; ++t) {
      float tmp[8];
      const float* rowC = Wc + (mt * 16 + e16) * (2 * H) + t * 32 + g * 4;
      *(f32x4*)(tmp) = *(const f32x4*)(rowC);
      *(f32x4*)(tmp + 4) = *(const f32x4*)(rowC + 16);
      wC1[mt][t] = pack8(tmp);
    }
  }
  __syncthreads();

  const int NTN = N_NODES / 16; // 6250
  for (int tile = wid; tile < NTN; tile += nw) {
    const int n0 = tile * 16;
    const float* base = nf + (long long)(n0 + e16) * ND;

    // B1 fragments from node_features (fp32 -> bf16), 4 k-steps
    bf16x8 b1[4];
#pragma unroll
    for (int t = 0; t < 4; ++t) {
      float tmp[8];
      *(f32x4*)(tmp) = *(const f32x4*)(base + t * 32 + g * 4);
      *(f32x4*)(tmp + 4) = *(const f32x4*)(base + t * 32 + 16 + g * 4);
      b1[t] = pack8(tmp);
    }

    // GEMM1: emb = relu(Wn @ nf^T + bn)
    f32x4 d1[4];
#pragma unroll
    for (int mt = 0; mt < 4; ++mt) d1[mt] = *(const f32x4*)(bshn + mt * 16 + g * 4);
#pragma unroll
    for (int t = 0; t < 4; ++t)
#pragma unroll
      for (int mt = 0; mt < 4; ++mt)
        d1[mt] = __builtin_amdgcn_mfma_f32_16x16x32_bf16(wN[mt][t], b1[t], d1[mt], 0, 0, 0);

    // relu in-place; lane-local chain into GEMM2 B operand
#pragma unroll
    for (int mt = 0; mt < 4; ++mt)
#pragma unroll
      for (int r = 0; r < 4; ++r) d1[mt][r] = fmaxf(d1[mt][r], 0.f);

    bf16x8 b2[2];
#pragma unroll
    for (int t = 0; t < 2; ++t) {
      float tmp[8];
#pragma unroll
      for (int i = 0; i < 4; ++i) {
        tmp[i] = d1[2 * t][i];
        tmp[4 + i] = d1[2 * t + 1][i];
      }
      b2[t] = pack8(tmp);
    }

    // GEMM2: T2 = Wc[:, :H] @ emb + bc
    f32x4 d2[4];
#pragma unroll
    for (int mt = 0; mt < 4; ++mt) d2[mt] = *(const f32x4*)(bshc + mt * 16 + g * 4);
#pragma unroll
    for (int t = 0; t < 2; ++t)
#pragma unroll
      for (int mt = 0; mt < 4; ++mt)
        d2[mt] = __builtin_amdgcn_mfma_f32_16x16x32_bf16(wC1[mt][t], b2[t], d2[mt], 0, 0, 0);

    // Posted-node mask for gated acc stores (bits 0..15)
    const unsigned long long pmask = __ballot(lane < 16 && pf[n0 + lane] != 0);

    // Pass 1: emb -> LDS transpose -> gated acc rows
#pragma unroll
    for (int mt = 0; mt < 4; ++mt)
#pragma unroll
      for (int r = 0; r < 4; ++r)
        myl[(mt * 16 + g * 4 + r) * 17 + e16] = d1[mt][r];
#pragma unroll
    for (int e = 0; e < 16; ++e)
      if ((pmask >> e) & 1)
        acc[(long long)(n0 + e) * H + lane] = myl[lane * 17 + e];

    // Pass 2: T2 -> LDS transpose -> all rows
#pragma unroll
    for (int mt = 0; mt < 4; ++mt)
#pragma unroll
      for (int r = 0; r < 4; ++r)
        myl[(mt * 16 + g * 4 + r) * 17 + e16] = d2[mt][r];
#pragma unroll
    for (int e = 0; e < 16; ++e)
      T2[(long long)(n0 + e) * H + lane] = myl[lane * 17 + e];
  }
}

// Sorted-order MFMA edge pipeline over the M filtered (posted-dst) edges.
__global__ void __launch_bounds__(256, 2) edge_kernel_sorted(
    const float* __restrict__ ea, const float* __restrict__ We,
    const float* __restrict__ be, const float* __restrict__ Wc,
    const float* __restrict__ T2, float* __restrict__ acc,
    const int4* __restrict__ eS, const int* __restrict__ Mp) {
  __shared__ float lds[4][64 * 17];
  __shared__ __attribute__((aligned(16))) float bsh[64];
  const int lane = threadIdx.x & 63;
  const int wslot = threadIdx.x >> 6;
  float* myl = lds[wslot];
  const int wid = blockIdx.x * 4 + wslot;
  const int nw = gridDim.x * 4;
  const int e16 = lane & 15;
  const int g = lane >> 4;

  if (threadIdx.x < 64) bsh[threadIdx.x] = be[threadIdx.x];

  bf16x8 wA[4][2], wC[4][2];
#pragma unroll
  for (int mt = 0; mt < 4; ++mt) {
#pragma unroll
    for (int t = 0; t < 2; ++t) {
      float tmp[8];
      const float* rowA = We + (mt * 16 + e16) * H + t * 32 + g * 4;
      *(f32x4*)(tmp) = *(const f32x4*)(rowA);
      *(f32x4*)(tmp + 4) = *(const f32x4*)(rowA + 16);
      wA[mt][t] = pack8(tmp);
      const float* rowC = Wc + (mt * 16 + e16) * (2 * H) + H + t * 32 + g * 4;
      *(f32x4*)(tmp) = *(const f32x4*)(rowC);
      *(f32x4*)(tmp + 4) = *(const f32x4*)(rowC + 16);
      wC[mt][t] = pack8(tmp);
    }
  }
  __syncthreads();

  const int M = Mp[0];
  const int ntiles = (M + 15) >> 4;
  const int chunk = (ntiles + nw - 1) / nw;
  const int t0 = wid * chunk;
  const int t1 = imin(t0 + chunk, ntiles);
  if (t0 >= t1) return;

  // Prologue: current tuple + ea data; next tuple. Clamp tail lanes.
  int4 eC = make_int4(0, 0, 0, 0);
  {
    const int i0 = t0 * 16 + e16;
    if (i0 < M) eC = eS[i0];
  }
  f32x4 eaC[4];
  {
    const float* base = ea + (long long)eC.x * H;
    eaC[0] = *(const f32x4*)(base + g * 4);
    eaC[1] = *(const f32x4*)(base + 16 + g * 4);
    eaC[2] = *(const f32x4*)(base + 32 + g * 4);
    eaC[3] = *(const f32x4*)(base + 48 + g * 4);
  }
  int4 eN = eC;
  if (t0 + 1 < t1) {
    const int i1 = (t0 + 1) * 16 + e16;
    eN = (i1 < M) ? eS[i1] : make_int4(0, 0, 0, 0);
  }

  int run_d = -1;
  float run_v = 0.f;

  for (int tile = t0; tile < t1; ++tile) {
    bf16x8 b1[2];
#pragma unroll
    for (int t = 0; t < 2; ++t) {
      float tmp[8];
#pragma unroll
      for (int i = 0; i < 4; ++i) {
        tmp[i] = eaC[t * 2][i];
        tmp[4 + i] = eaC[t * 2 + 1][i];
      }
      b1[t] = pack8(tmp);
    }
    const int srcc = eC.y;
    const int dstc = eC.z;

    if (tile + 1 < t1) {
      const float* base = ea + (long long)eN.x * H;
      eaC[0] = *(const f32x4*)(base + g * 4);
      eaC[1] = *(const f32x4*)(base + 16 + g * 4);
      eaC[2] = *(const f32x4*)(base + 32 + g * 4);
      eaC[3] = *(const f32x4*)(base + 48 + g * 4);
    }
    eC = eN;
    if (tile + 2 < t1) {
      const int i2 = (tile + 2) * 16 + e16;
      eN = (i2 < M) ? eS[i2] : make_int4(0, 0, 0, 0);
    }

    // GEMM1: he = relu(We @ ea^T + be)
    f32x4 d1[4];
#pragma unroll
    for (int mt = 0; mt < 4; ++mt) d1[mt] = *(const f32x4*)(bsh + mt * 16 + g * 4);
#pragma unroll
    for (int t = 0; t < 2; ++t)
#pragma unroll
      for (int mt = 0; mt < 4; ++mt)
        d1[mt] = __builtin_amdgcn_mfma_f32_16x16x32_bf16(wA[mt][t], b1[t], d1[mt], 0, 0, 0);

    bf16x8 b2[2];
#pragma unroll
    for (int t = 0; t < 2; ++t) {
      float tmp[8];
#pragma unroll
      for (int i = 0; i < 4; ++i) {
        tmp[i] = fmaxf(d1[2 * t][i], 0.f);
        tmp[4 + i] = fmaxf(d1[2 * t + 1][i], 0.f);
      }
      b2[t] = pack8(tmp);
    }

    // GEMM2 streamed per-mt into LDS transpose (stride 17)
#pragma unroll
    for (int mt = 0; mt < 4; ++mt) {
      f32x4 d2 = (f32x4){0.f, 0.f, 0.f, 0.f};
      d2 = __builtin_amdgcn_mfma_f32_16x16x32_bf16(wC[mt][0], b2[0], d2, 0, 0, 0);
      d2 = __builtin_amdgcn_mfma_f32_16x16x32_bf16(wC[mt][1], b2[1], d2, 0, 0, 0);
#pragma unroll
      for (int r = 0; r < 4; ++r)
        myl[(mt * 16 + g * 4 + r) * 17 + e16] = d2[r];
    }

    // Scatter: 8 independent T2 gathers in flight, then register run-accumulate.
    const int nval = imin(16, M - tile * 16);
#pragma unroll
    for (int half = 0; half < 2; ++half) {
      float mv[8];
#pragma unroll
      for (int e = 0; e < 8; ++e) {
        const int s = __builtin_amdgcn_readlane(srcc, half * 8 + e);
        mv[e] = myl[lane * 17 + half * 8 + e] + T2[(long long)s * H + lane];
      }
      const int hi = imin(8, nval - half * 8);
      for (int e = 0; e < hi; ++e) {
        const int d = __builtin_amdgcn_readlane(dstc, half * 8 + e);
        if (d != run_d) {
          if (run_d >= 0) atomicAdd(&acc[(long long)run_d * H + lane], run_v);
          run_d = d;
          run_v = mv[e];
        } else {
          run_v += mv[e];
        }
      }
    }
  }
  if (run_d >= 0) atomicAdd(&acc[(long long)run_d * H + lane], run_v);
}

// ---- Fallback path (unfiltered, fp32 node) — only if ws can't fit buffers ----
__global__ void __launch_bounds__(256, 2) node_kernel(
    const float* __restrict__ nf, const float* __restrict__ Wn,
    const float* __restrict__ bn, const float* __restrict__ Wc,
    const float* __restrict__ bc, float* __restrict__ acc,
    float* __restrict__ T2) {
  const int lane = threadIdx.x & 63;
  const int wid = blockIdx.x * (blockDim.x >> 6) + (threadIdx.x >> 6);
  const int nw = gridDim.x * (blockDim.x >> 6);

  float wn[ND];
#pragma unroll
  for (int i = 0; i < ND / 4; ++i) {
    float4 v = ((const float4*)(Wn + lane * ND))[i];
    wn[4 * i] = v.x; wn[4 * i + 1] = v.y; wn[4 * i + 2] = v.z; wn[4 * i + 3] = v.w;
  }
  float wc[H];
#pragma unroll
  for (int i = 0; i < H / 4; ++i) {
    float4 v = ((const float4*)(Wc + lane * 2 * H))[i];
    wc[4 * i] = v.x; wc[4 * i + 1] = v.y; wc[4 * i + 2] = v.z; wc[4 * i + 3] = v.w;
  }
  const float bnl = bn[lane];
  const float bcl = bc[lane];

  for (int n = wid; n < N_NODES; n += nw) {
    const float xa = nf[(long long)n * ND + lane];
    const float xb = nf[(long long)n * ND + 64 + lane];
    float a0 = 0.f, a1 = 0.f, a2 = 0.f, a3 = 0.f;
#pragma unroll
    for (int k = 0; k < 64; k += 4) {
      a0 = fmaf(bcastf(xa, k + 0), wn[k + 0], a0);
      a1 = fmaf(bcastf(xa, k + 1), wn[k + 1], a1);
      a2 = fmaf(bcastf(xa, k + 2), wn[k + 2], a2);
      a3 = fmaf(bcastf(xa, k + 3), wn[k + 3], a3);
    }
#pragma unroll
    for (int k = 0; k < 64; k += 4) {
      a0 = fmaf(bcastf(xb, k + 0), wn[64 + k + 0], a0);
      a1 = fmaf(bcastf(xb, k + 1), wn[64 + k + 1], a1);
      a2 = fmaf(bcastf(xb, k + 2), wn[64 + k + 2], a2);
      a3 = fmaf(bcastf(xb, k + 3), wn[64 + k + 3], a3);
    }
    float e = fmaxf(a0 + a1 + a2 + a3 + bnl, 0.f);

    float t0 = 0.f, t1 = 0.f, t2 = 0.f, t3 = 0.f;
#pragma unroll
    for (int j = 0; j < 64; j += 4) {
      t0 = fmaf(bcastf(e, j + 0), wc[j + 0], t0);
      t1 = fmaf(bcastf(e, j + 1), wc[j + 1], t1);
      t2 = fmaf(bcastf(e, j + 2), wc[j + 2], t2);
      t3 = fmaf(bcastf(e, j + 3), wc[j + 3], t3);
    }
    float t = t0 + t1 + t2 + t3 + bcl;

    acc[(long long)n * H + lane] = e;
    T2[(long long)n * H + lane] = t;
  }
}

__global__ void __launch_bounds__(256, 2) edge_kernel(
    const void* __restrict__ eidx, const float* __restrict__ ea,
    const float* __restrict__ We, const float* __restrict__ be,
    const float* __restrict__ Wc, const float* __restrict__ T2,
    float* __restrict__ acc, const int* __restrict__ flag) {
  __shared__ float lds[4][64 * 17];
  const int lane = threadIdx.x & 63;
  const int wslot = threadIdx.x >> 6;
  float* myl = lds[wslot];
  const int wid = blockIdx.x * 4 + wslot;
  const int nw = gridDim.x * 4;
  const int is64 = flag[0];
  const int e16 = lane & 15;
  const int g = lane >> 4;
  const int NT = N_EDGES / 16;

  bf16x8 wA[4][2], wC[4][2];
#pragma unroll
  for (int mt = 0; mt < 4; ++mt) {
#pragma unroll
    for (int t = 0; t < 2; ++t) {
      float tmp[8];
      const float* rowA = We + (mt * 16 + e16) * H + t * 32 + g * 4;
      *(f32x4*)(tmp) = *(const f32x4*)(rowA);
      *(f32x4*)(tmp + 4) = *(const f32x4*)(rowA + 16);
      wA[mt][t] = pack8(tmp);
      const float* rowC = Wc + (mt * 16 + e16) * (2 * H) + H + t * 32 + g * 4;
      *(f32x4*)(tmp) = *(const f32x4*)(rowC);
      *(f32x4*)(tmp + 4) = *(const f32x4*)(rowC + 16);
      wC[mt][t] = pack8(tmp);
    }
  }
  f32x4 bias[4];
#pragma unroll
  for (int mt = 0; mt < 4; ++mt)
#pragma unroll
    for (int r = 0; r < 4; ++r) bias[mt][r] = be[mt * 16 + g * 4 + r];

  f32x4 ean[4];
  int srcn = 0, dstn = 0;
  int tile = wid;
  if (tile < NT) {
    const float* base = ea + (long long)(tile * 16 + e16) * H;
#pragma unroll
    for (int t = 0; t < 2; ++t) {
      ean[t * 2] = *(const f32x4*)(base + t * 32 + g * 4);
      ean[t * 2 + 1] = *(const f32x4*)(base + t * 32 + 16 + g * 4);
    }
    srcn = load_idx(eidx, (long long)tile * 16 + e16, is64);
    dstn = load_idx(eidx, (long long)N_EDGES + (long long)tile * 16 + e16, is64);
  }

  for (; tile < NT; tile += nw) {
    f32x4 eac[4];
#pragma unroll
    for (int i = 0; i < 4; ++i) eac[i] = ean[i];
    const int srcc = srcn, dstc = dstn;

    const int tn = tile + nw;
    if (tn < NT) {
      const float* base = ea + (long long)(tn * 16 + e16) * H;
#pragma unroll
      for (int t = 0; t < 2; ++t) {
        ean[t * 2] = *(const f32x4*)(base + t * 32 + g * 4);
        ean[t * 2 + 1] = *(const f32x4*)(base + t * 32 + 16 + g * 4);
      }
      srcn = load_idx(eidx, (long long)tn * 16 + e16, is64);
      dstn = load_idx(eidx, (long long)N_EDGES + (long long)tn * 16 + e16, is64);
    }

    bf16x8 b1[2];
#pragma unroll
    for (int t = 0; t < 2; ++t) {
      float tmp[8];
#pragma unroll
      for (int i = 0; i < 4; ++i) {
        tmp[i] = eac[t * 2][i];
        tmp[4 + i] = eac[t * 2 + 1][i];
      }
      b1[t] = pack8(tmp);
    }

    f32x4 d1[4];
#pragma unroll
    for (int mt = 0; mt < 4; ++mt) d1[mt] = bias[mt];
#pragma unroll
    for (int t = 0; t < 2; ++t)
#pragma unroll
      for (int mt = 0; mt < 4; ++mt)
        d1[mt] = __builtin_amdgcn_mfma_f32_16x16x32_bf16(wA[mt][t], b1[t], d1[mt], 0, 0, 0);

    bf16x8 b2[2];
#pragma unroll
    for (int t = 0; t < 2; ++t) {
      float tmp[8];
#pragma unroll
      for (int i = 0; i < 4; ++i) {
        tmp[i] = fmaxf(d1[2 * t][i], 0.f);
        tmp[4 + i] = fmaxf(d1[2 * t + 1][i], 0.f);
      }
      b2[t] = pack8(tmp);
    }

    f32x4 d2[4];
#pragma unroll
    for (int mt = 0; mt < 4; ++mt) d2[mt] = (f32x4){0.f, 0.f, 0.f, 0.f};
#pragma unroll
    for (int t = 0; t < 2; ++t)
#pragma unroll
      for (int mt = 0; mt < 4; ++mt)
        d2[mt] = __builtin_amdgcn_mfma_f32_16x16x32_bf16(wC[mt][t], b2[t], d2[mt], 0, 0, 0);

#pragma unroll
    for (int mt = 0; mt < 4; ++mt)
#pragma unroll
      for (int r = 0; r < 4; ++r)
        myl[(mt * 16 + g * 4 + r) * 17 + e16] = d2[mt][r];

#pragma unroll
    for (int e = 0; e < 16; ++e) {
      const int s = __builtin_amdgcn_readlane(srcc, e);
      const int d = __builtin_amdgcn_readlane(dstc, e);
      const float m = myl[lane * 17 + e] + T2[(long long)s * H + lane];
      atomicAdd(&acc[(long long)d * H + lane], m);
    }
  }
}

// Per-post: logit = dot(acc[idx], W_out) + b_out; out = sigmoid(logit)
__global__ void __launch_bounds__(256) out_kernel(
    const void* __restrict__ pidx, const float* __restrict__ acc,
    const float* __restrict__ Wo, const float* __restrict__ bo,
    float* __restrict__ out, const int* __restrict__ flag) {
  const int lane = threadIdx.x & 63;
  const int w = blockIdx.x * (blockDim.x >> 6) + (threadIdx.x >> 6);
  if (w >= N_POSTS) return;
  const int is64 = flag[0];
  const int idx = load_idx(pidx, w, is64);
  float v = acc[(long long)idx * H + lane] * Wo[lane];
#pragma unroll
  for (int s = 32; s > 0; s >>= 1) v += __shfl_xor(v, s, 64);
  if (lane == 0) {
    float logit = v + bo[0];
    out[w] = 1.f / (1.f + expf(-logit));
  }
}

extern "C" void kernel_launch(void* const* d_in, const int* in_sizes, int n_in,
                              void* d_out, int out_size, void* d_ws, size_t ws_size,
                              hipStream_t stream) {
  const float* nf = (const float*)d_in[0];
  const void* eidx = d_in[1];
  const float* ea = (const float*)d_in[2];
  const void* pidx = d_in[3];
  const float* Wn = (const float*)d_in[4];
  const float* bn = (const float*)d_in[5];
  const float* We = (const float*)d_in[6];
  const float* be = (const float*)d_in[7];
  const float* Wc = (const float*)d_in[8];
  const float* bc = (const float*)d_in[9];
  const float* Wo = (const float*)d_in[10];
  const float* bo = (const float*)d_in[11];
  float* out = (float*)d_out;

  float* acc = (float*)d_ws;                     // [N,H]
  float* T2 = acc + (size_t)N_NODES * H;         // [N,H]
  int4* eS = (int4*)(T2 + (size_t)N_NODES * H);  // [E] sorted tuples, 16B-aligned
  int* cnt = (int*)(eS + N_EDGES);               // [N]
  int* pf = cnt + N_NODES;                       // [N] posted-node flags
  int* btot = pf + N_NODES;                      // [128]
  int* Mp = btot + 128;                          // [1]
  int* flag = Mp + 1;                            // [1]

  const size_t need_sorted = (size_t)2 * N_NODES * H * 4 + (size_t)N_EDGES * 16 +
                             (size_t)2 * N_NODES * 4 + 128 * 4 + 8;

  if (ws_size >= need_sorted) {
    init_kernel<<<(2 * N_NODES + 255) / 256, 256, 0, stream>>>(eidx, cnt, flag);
    mark_kernel<<<(N_POSTS + 255) / 256, 256, 0, stream>>>(pidx, pf, flag);
    hist_kernel<<<2048, 256, 0, stream>>>(eidx, cnt, pf, flag);
    scan_block_kernel<<<SCAN_NB, SCAN_B, 0, stream>>>(cnt, btot);
    scan_add_kernel<<<SCAN_NB, SCAN_B, 0, stream>>>(cnt, btot, Mp);
    scatter_kernel<<<2048, 256, 0, stream>>>(eidx, cnt, pf, eS, flag);
    node_kernel_mfma<<<512, 256, 0, stream>>>(nf, Wn, bn, Wc, bc, pf, acc, T2);
    edge_kernel_sorted<<<512, 256, 0, stream>>>(ea, We, be, Wc, T2, acc, eS, Mp);
    out_kernel<<<(N_POSTS + 3) / 4, 256, 0, stream>>>(pidx, acc, Wo, bo, out, flag);
  } else {
    int* flag2 = (int*)(T2 + (size_t)N_NODES * H);
    init_kernel<<<1, 256, 0, stream>>>(eidx, flag2 - 1, flag2); // detect only
    node_kernel<<<1024, 256, 0, stream>>>(nf, Wn, bn, Wc, bc, acc, T2);
    edge_kernel<<<1024, 256, 0, stream>>>(eidx, ea, We, be, Wc, T2, acc, flag2);
    out_kernel<<<(N_POSTS + 3) / 4, 256, 0, stream>>>(pidx, acc, Wo, bo, out, flag2);
  }
}